// Round 10
// baseline (277.448 us; speedup 1.0000x reference)
//
#include <hip/hip_runtime.h>

// ---------------------------------------------------------------------------
// PointTransformerForSegmentation, round 15:
//   prep      : MERGED convert (bf16 casts) + knn_pos (kNN + pos embed) in
//               one launch, partitioned by blockIdx (fewer kernel boundaries).
//   fgemm     : F[b*128+n2][512] = feat2 . W0feat^T   (f32, tiny GEMM)
//   h0        : streaming H0 = relu((F[idx] + posw.W0p^T)*s0+b0), zero LDS.
//   gemm2     : B-DIRECT hybrid. A (H0) staged in LDS (16KB/step, triple
//               buffer, in-place restage, counted vmcnt(12)); B (W1, 1MB,
//               L2-resident) loaded DIRECTLY global->VGPR as MFMA fragments
//               (16 rows x 64B segments), double-buffered in registers and
//               prefetched 1 step ahead -> compiler emits counted per-MFMA
//               vmcnt waits; B is fully decoupled from the barrier path.
//               24 K-steps (3 planes x 8 of BK=64), 32 MFMA/wave/step,
//               register relu-fold at kt=7/15/23. R4 epilogue.
// LDS layout: fragment-linear 1KB groups (16 rows x 32 k), lane l at
// group*1024 + l*16 -> sequential banks, zero conflicts.
// ---------------------------------------------------------------------------

typedef unsigned short u16;
typedef __bf16 bf16x8 __attribute__((ext_vector_type(8)));
typedef float f32x4 __attribute__((ext_vector_type(4)));
typedef u16 u16x4 __attribute__((ext_vector_type(4)));
typedef u16 u16x8 __attribute__((ext_vector_type(8)));

#define BQ 8
#define N1Q 2048
#define N2Q 128
#define C2Q 256
#define DPOS 32
#define H0Q 512
#define H1Q 1024
#define NQ (BQ * N1Q)   // 16384 queries

// workspace layout (bytes)
#define WS_W0F 0u          // 512*256*2   = 262144
#define WS_W0P 262144u     // 512*32*2    = 32768
#define WS_W1 294912u      // 1024*512*2  = 1048576
#define WS_F2B 1343488u    // 1024*256*2  = 524288
#define WS_F 1867776u      // 1024*512*4  = 2097152
#define WS_H0 3964928u     // 3*16384*512*2 = 50331648
#define WS_POS 54296576u   // 3*16384*32*2 = 3145728
#define WS_IDX 57442304u   // 3*16384*4   = 196608 (end 57638912)

__device__ __forceinline__ u16 f2bf(float f) {
  unsigned int u = __builtin_bit_cast(unsigned int, f);
  return (u16)((u + 0x7FFFu + ((u >> 16) & 1u)) >> 16);
}

__device__ __forceinline__ void load16_lds(const void* g, void* l) {
  __builtin_amdgcn_global_load_lds(
      (const __attribute__((address_space(1))) unsigned int*)g,
      (__attribute__((address_space(3))) unsigned int*)l, 16, 0, 0);
}

// ---------------------------------------------------------------------------
// prep: blocks 0..127 = kNN + pos embed (128 queries/block); blocks 128..1951
// = bf16 conversions (512 elems/block). Per-block-uniform branch, so the
// __syncthreads in the knn part never diverges within a block.
__global__ __launch_bounds__(512, 2) void prep(
    const float* __restrict__ xyz1, const float* __restrict__ xyz2,
    const float* __restrict__ lrf2, const float* __restrict__ w_pos,
    const float* __restrict__ pscale, const float* __restrict__ pbias,
    const float* __restrict__ w0, const float* __restrict__ w1,
    const float* __restrict__ feat2,
    u16* __restrict__ posw, int* __restrict__ idxw,
    u16* __restrict__ w0f, u16* __restrict__ w0p,
    u16* __restrict__ w1b, u16* __restrict__ f2b) {
  if (blockIdx.x >= 128) {
    int i = (blockIdx.x - 128) * 512 + threadIdx.x;  // < 933888 exactly
    if (i < 131072) {
      int h = i >> 8, c = i & 255;
      w0f[i] = f2bf(w0[h * 288 + c]);
    } else if (i < 147456) {
      int j = i - 131072;
      int h = j >> 5, c = j & 31;
      w0p[j] = f2bf(w0[h * 288 + 256 + c]);
    } else if (i < 671744) {
      int j = i - 147456;
      w1b[j] = f2bf(w1[j]);
    } else {
      int j = i - 671744;  // < 262144
      f2b[j] = f2bf(feat2[j]);
    }
    return;
  }

  __shared__ float xyz2s[N2Q * 3];
  __shared__ float n2s[N2Q];
  __shared__ float lrfs[N2Q * 9];
  __shared__ float wps[DPOS * 4];
  __shared__ float pss[DPOS];
  __shared__ float pbs[DPOS];
  __shared__ float candd[128 * 13];  // stride 13: conflict-free merge reads
  __shared__ int candi[128 * 13];
  __shared__ int idxb[384];

  const int t = threadIdx.x;
  const int qb = blockIdx.x * 128;   // 128 knn blocks
  const int b = qb >> 11;

  for (int i = t; i < N2Q * 3; i += 512) xyz2s[i] = xyz2[b * N2Q * 3 + i];
  for (int i = t; i < N2Q * 9; i += 512) lrfs[i] = lrf2[b * N2Q * 9 + i];
  if (t < DPOS * 4) wps[t] = w_pos[t];
  if (t < DPOS) { pss[t] = pscale[t]; pbs[t] = pbias[t]; }
  __syncthreads();
  if (t < N2Q) {
    float x = xyz2s[t * 3], y = xyz2s[t * 3 + 1], z = xyz2s[t * 3 + 2];
    n2s[t] = x * x + y * y + z * z;
  }
  __syncthreads();

  // ---- 1a: partial kNN, 4 threads per query ----
  {
    const int ql = t >> 2, qt = t & 3;
    const int q = qb + ql;
    const float px = xyz1[q * 3], py = xyz1[q * 3 + 1], pz = xyz1[q * 3 + 2];
    const float pn = px * px + py * py + pz * pz;
    float d0 = 1e30f, d1 = 1e30f, d2v = 1e30f;
    int i0 = 0, i1 = 0, i2 = 0;
    const int ibeg = qt * 32;
    for (int i = ibeg; i < ibeg + 32; i++) {
      float dt = px * xyz2s[i * 3] + py * xyz2s[i * 3 + 1] + pz * xyz2s[i * 3 + 2];
      float d = pn + n2s[i] - 2.f * dt;
      if (d < d0) {
        d2v = d1; i2 = i1; d1 = d0; i1 = i0; d0 = d; i0 = i;
      } else if (d < d1) {
        d2v = d1; i2 = i1; d1 = d; i1 = i;
      } else if (d < d2v) {
        d2v = d; i2 = i;
      }
    }
    int base = ql * 13 + qt * 3;
    candd[base] = d0;      candi[base] = i0;
    candd[base + 1] = d1;  candi[base + 1] = i1;
    candd[base + 2] = d2v; candi[base + 2] = i2;
  }
  __syncthreads();

  // ---- 1b: merge 12 candidates per query (t<128), serial tie order ----
  if (t < 128) {
    float d0 = 1e30f, d1 = 1e30f, d2v = 1e30f;
    int i0 = 0, i1 = 0, i2 = 0;
    int base = t * 13;
#pragma unroll
    for (int c = 0; c < 12; c++) {
      float d = candd[base + c];
      int id = candi[base + c];
      if (d < d0) {
        d2v = d1; i2 = i1; d1 = d0; i1 = i0; d0 = d; i0 = id;
      } else if (d < d1) {
        d2v = d1; i2 = i1; d1 = d; i1 = id;
      } else if (d < d2v) {
        d2v = d; i2 = id;
      }
    }
    idxb[t] = i0;
    idxb[128 + t] = i1;
    idxb[256 + t] = i2;
  }
  __syncthreads();

  // ---- 1c: pos embed, one (query, neighbor) per thread (t<384) ----
  if (t < 384) {
    const int j = t >> 7, ql = t & 127;
    const int q = qb + ql;
    const float px = xyz1[q * 3], py = xyz1[q * 3 + 1], pz = xyz1[q * 3 + 2];
    const int id = idxb[j * 128 + ql];
    float rx = px - xyz2s[id * 3];
    float ry = py - xyz2s[id * 3 + 1];
    float rz = pz - xyz2s[id * 3 + 2];
    float rn = sqrtf(rx * rx + ry * ry + rz * rz);
    float inv = 1.f / fmaxf(rn, 1e-12f);
    float ux = rx * inv, uy = ry * inv, uz = rz * inv;
    const float* L = lrfs + id * 9;
    float a0 = L[0] * ux + L[1] * uy + L[2] * uz;
    float a1 = L[3] * ux + L[4] * uy + L[5] * uz;
    float a2 = L[6] * ux + L[7] * uy + L[8] * uz;
    const size_t row = (size_t)j * NQ + q;
    idxw[row] = id;
#pragma unroll
    for (int c = 0; c < 4; c++) {
      u16x8 chunk;
#pragma unroll
      for (int e = 0; e < 8; e++) {
        int o = c * 8 + e;
        float v = wps[o * 4] * rn + wps[o * 4 + 1] * a0 + wps[o * 4 + 2] * a1 +
                  wps[o * 4 + 3] * a2;
        v = v * pss[o] + pbs[o];
        v = (v >= 0.f) ? v : 0.2f * v;  // LeakyReLU(0.2)
        chunk[e] = f2bf(v);
      }
      *(u16x8*)(posw + row * 32 + c * 8) = chunk;
    }
  }
}

// ---------------------------------------------------------------------------
// fgemm: F[m][n] = sum_k feat2bf[m][k]*w0featbf[n][k], f32 out.
// M=1024 N=512 K=256, 128x128 tile, 32 blocks.
__global__ __launch_bounds__(256, 2) void fgemm(const u16* __restrict__ A,
                                                const u16* __restrict__ W,
                                                float* __restrict__ F) {
  __shared__ alignas(16) u16 As[128 * 32];
  __shared__ alignas(16) u16 Bs[128 * 32];
  const int m0 = (blockIdx.x >> 2) * 128, n0 = (blockIdx.x & 3) * 128;
  const int t = threadIdx.x;
  const int wv = t >> 6, lane = t & 63;
  const int wm = wv >> 1, wn = wv & 1;
  const int quad = lane >> 4, cc = lane & 15;
  const int srow = lane & 15, skc = quad * 8;
  f32x4 acc[4][4] = {};

  for (int k0 = 0; k0 < 256; k0 += 32) {
#pragma unroll
    for (int i = 0; i < 2; i++) {
      int g = i * 4 + wv;
      load16_lds(A + (size_t)(m0 + g * 16 + srow) * 256 + k0 + skc,
                 (char*)As + g * 1024 + (lane << 4));
      load16_lds(W + (size_t)(n0 + g * 16 + srow) * 256 + k0 + skc,
                 (char*)Bs + g * 1024 + (lane << 4));
    }
    __syncthreads();
    bf16x8 af[4], bf[4];
#pragma unroll
    for (int mt = 0; mt < 4; mt++)
      af[mt] = *(const bf16x8*)((const char*)As + (wm * 4 + mt) * 1024 + (lane << 4));
#pragma unroll
    for (int nt = 0; nt < 4; nt++)
      bf[nt] = *(const bf16x8*)((const char*)Bs + (wn * 4 + nt) * 1024 + (lane << 4));
#pragma unroll
    for (int mt = 0; mt < 4; mt++)
#pragma unroll
      for (int nt = 0; nt < 4; nt++)
        acc[mt][nt] = __builtin_amdgcn_mfma_f32_16x16x32_bf16(
            af[mt], bf[nt], acc[mt][nt], 0, 0, 0);
    __syncthreads();
  }

#pragma unroll
  for (int nt = 0; nt < 4; nt++) {
    int gn = n0 + wn * 64 + nt * 16 + cc;
#pragma unroll
    for (int mt = 0; mt < 4; mt++) {
      int gm = m0 + wm * 64 + mt * 16 + quad * 4;
#pragma unroll
      for (int r = 0; r < 4; r++)
        F[(size_t)(gm + r) * H0Q + gn] = acc[mt][nt][r];
    }
  }
}

// ---------------------------------------------------------------------------
// h0: streaming H0 build, zero LDS, 768 blocks x 256 threads (4 waves).
__global__ __launch_bounds__(256, 4) void h0_kernel(
    const u16* __restrict__ posw, const int* __restrict__ idxw,
    const u16* __restrict__ w0p, const float* __restrict__ F,
    const float* __restrict__ s0, const float* __restrict__ b0,
    u16* __restrict__ H0) {
  const int t = threadIdx.x;
  const int wv = t >> 6, lane = t & 63;
  const int quad = lane >> 4, cc = lane & 15;
  const int r0 = (blockIdx.x * 4 + wv) * 16;  // 768*4*16 = 49152 rows

  const int r = r0 + cc;               // this lane's row
  const int q = r & (NQ - 1);
  const int bb = q >> 11;
  const int idv = idxw[r];
  const float* Fr = F + ((size_t)(bb * N2Q + idv)) * H0Q;
  u16* Hr = H0 + (size_t)r * H0Q;

  const bf16x8 afr = *(const bf16x8*)(posw + (size_t)r * 32 + quad * 8);
  const f32x4 zf = {};

#pragma unroll 4
  for (int nt = 0; nt < 32; nt++) {
    const bf16x8 bfr = *(const bf16x8*)(w0p + (nt * 16 + cc) * 32 + quad * 8);
    f32x4 acc = __builtin_amdgcn_mfma_f32_16x16x32_bf16(bfr, afr, zf, 0, 0, 0);
    const int hb = nt * 16 + quad * 4;
    const f32x4 sv = *(const f32x4*)(s0 + hb);
    const f32x4 bv = *(const f32x4*)(b0 + hb);
    const f32x4 fv = *(const f32x4*)(Fr + hb);
    u16x4 o4;
#pragma unroll
    for (int e = 0; e < 4; e++) {
      float h = (fv[e] + acc[e]) * sv[e] + bv[e];
      h = h > 0.f ? h : 0.f;
      o4[e] = f2bf(h);
    }
    *(u16x4*)(Hr + hb) = o4;
  }
}

// ---------------------------------------------------------------------------
// gemm2: out[b][n][n1] = sum_j relu((H0_j[q][:] . W1[n][:])*s1[n] + b1[n]).
// BM=128 x BN=256, BK=64, 512 thr (8 waves 2Mx4N, 64x64/wave).
// A in LDS: 16KB/step, triple buffer, in-place restage (R4 discipline),
// uniform counted vmcnt(12) (= 2x2 A-stage loads + 8 B loads in flight).
// B DIRECT from global (W1 L2-resident): bf fragments double-buffered in
// VGPRs, prefetched 1 step ahead; compiler inserts counted waits for them.
// 24 K-steps = 3 planes x 8; register relu-fold at kt=7/15/23.
__global__ __launch_bounds__(512, 2) void gemm2(const u16* __restrict__ A,
                                                const u16* __restrict__ W,
                                                const float* __restrict__ s,
                                                const float* __restrict__ bz,
                                                float* __restrict__ out) {
  __shared__ alignas(16) u16 As[3][128 * 64];  // 16 KB x 3
  const int id = blockIdx.x;            // 512 blocks
  const int xcd = id & 7, g = id >> 3;  // g 0..63
  const int m0 = (xcd * 16 + (g >> 2)) * 128;  // 16 m-tiles per XCD
  const int n0 = (g & 3) * 256;                // 4 n-blocks share m0 per XCD
  const int t = threadIdx.x;
  const int wv = t >> 6, lane = t & 63;
  const int wm = wv >> 2, wn = wv & 3;  // 2M x 4N wave grid
  const int quad = lane >> 4, cc = lane & 15;
  const int lr = lane & 15, lk = quad * 8;

  const size_t aOff = (size_t)(m0 + wv * 16 + lr) * 512 + lk;
  // B direct-row bases: lane reads 16B of W1 row gn at col (k0 + kk*32 + quad*8)
  const u16* Wrow[4];
#pragma unroll
  for (int nt = 0; nt < 4; nt++)
    Wrow[nt] = W + (size_t)(n0 + wn * 64 + nt * 16 + cc) * 512 + quad * 8;

  float sv[4], bv[4];
#pragma unroll
  for (int nt = 0; nt < 4; nt++) {
    int gn = n0 + wn * 64 + nt * 16 + cc;
    sv[nt] = s[gn];
    bv[nt] = bz[gn];
  }
  // pin s/b so no vmcnt(0) drain lands inside the pipelined loop
#pragma unroll
  for (int nt = 0; nt < 4; nt++) {
    float a = sv[nt], c = bv[nt];
    asm volatile("" : "+v"(a), "+v"(c));
    sv[nt] = a; bv[nt] = c;
  }

  auto stageA = [&](int kt) {
    const u16* Ap = A + (size_t)(kt >> 3) * ((size_t)NQ * H0Q) + ((kt & 7) << 6);
    char* ab = (char*)As[kt % 3] + (lane << 4);
    load16_lds(Ap + aOff, ab + wv * 1024);           // kk=0 group wv
    load16_lds(Ap + aOff + 32, ab + (8 + wv) * 1024);  // kk=1 group 8+wv
  };

  auto loadB = [&](int kt, bf16x8 bf[2][4]) {
    const int k0 = (kt & 7) << 6;
#pragma unroll
    for (int kk = 0; kk < 2; kk++)
#pragma unroll
      for (int nt = 0; nt < 4; nt++)
        bf[kk][nt] = *(const bf16x8*)(Wrow[nt] + k0 + kk * 32);
  };

  f32x4 sum[4][4] = {};
  f32x4 acc[4][4] = {};

  auto fold = [&]() {
#pragma unroll
    for (int mt = 0; mt < 4; mt++)
#pragma unroll
      for (int nt = 0; nt < 4; nt++) {
#pragma unroll
        for (int r = 0; r < 4; r++) {
          float h = acc[mt][nt][r] * sv[nt] + bv[nt];
          sum[mt][nt][r] += (h > 0.f ? h : 0.f);
        }
        acc[mt][nt] = f32x4{};
      }
  };

  bf16x8 bfA[2][4], bfB[2][4];
  stageA(0);
  stageA(1);
  stageA(2);
  loadB(0, bfA);

  auto step = [&](int kt, bf16x8 bfCur[2][4], bf16x8 bfNxt[2][4]) {
    asm volatile("s_waitcnt vmcnt(12)" ::: "memory");  // A-stage kt landed
    __builtin_amdgcn_s_barrier();
    bf16x8 af[2][4];
    const char* ab = (const char*)As[kt % 3] + (lane << 4);
#pragma unroll
    for (int kk = 0; kk < 2; kk++)
#pragma unroll
      for (int mt = 0; mt < 4; mt++)
        af[kk][mt] = *(const bf16x8*)(ab + (kk * 8 + wm * 4 + mt) * 1024);
    asm volatile("s_waitcnt lgkmcnt(0)" ::: "memory");
    __builtin_amdgcn_s_barrier();                     // all waves read buf
    if (kt + 3 < 24) stageA(kt + 3);                  // in-place restage
    if (kt + 1 < 24) loadB(kt + 1, bfNxt);            // B prefetch (VGPR)
    __builtin_amdgcn_s_setprio(1);
#pragma unroll
    for (int kk = 0; kk < 2; kk++)
#pragma unroll
      for (int mt = 0; mt < 4; mt++)
#pragma unroll
        for (int nt = 0; nt < 4; nt++)
          acc[mt][nt] = __builtin_amdgcn_mfma_f32_16x16x32_bf16(
              af[kk][mt], bfCur[kk][nt], acc[mt][nt], 0, 0, 0);
    __builtin_amdgcn_s_setprio(0);
    if ((kt & 7) == 7) fold();  // kt 7, 15, 23
  };

  for (int kp = 0; kp < 12; kp++) {
    step(2 * kp, bfA, bfB);
    step(2 * kp + 1, bfB, bfA);
  }

#pragma unroll
  for (int nt = 0; nt < 4; nt++) {
    int gn = n0 + wn * 64 + nt * 16 + cc;
#pragma unroll
    for (int mt = 0; mt < 4; mt++) {
      int gm = m0 + wm * 64 + mt * 16 + quad * 4;
#pragma unroll
      for (int r = 0; r < 4; r++) {
        int q = gm + r;
        out[((size_t)(q >> 11) * H1Q + gn) * N1Q + (q & 2047)] = sum[mt][nt][r];
      }
    }
  }
}

// ---------------------------------------------------------------------------
extern "C" void kernel_launch(void* const* d_in, const int* in_sizes, int n_in,
                              void* d_out, int out_size, void* d_ws,
                              size_t ws_size, hipStream_t stream) {
  const float* xyz1 = (const float*)d_in[0];
  const float* xyz2 = (const float*)d_in[1];
  const float* feat2 = (const float*)d_in[2];
  const float* lrf2 = (const float*)d_in[3];
  const float* w_pos = (const float*)d_in[4];
  const float* pscale = (const float*)d_in[5];
  const float* pbias = (const float*)d_in[6];
  const float* w0 = (const float*)d_in[7];
  const float* s0 = (const float*)d_in[8];
  const float* b0 = (const float*)d_in[9];
  const float* w1 = (const float*)d_in[10];
  const float* s1 = (const float*)d_in[11];
  const float* b1 = (const float*)d_in[12];
  float* out = (float*)d_out;

  char* ws = (char*)d_ws;
  u16* w0f = (u16*)(ws + WS_W0F);
  u16* w0p = (u16*)(ws + WS_W0P);
  u16* w1b = (u16*)(ws + WS_W1);
  u16* f2b = (u16*)(ws + WS_F2B);
  float* F = (float*)(ws + WS_F);
  u16* H0 = (u16*)(ws + WS_H0);
  u16* posw = (u16*)(ws + WS_POS);
  int* idxw = (int*)(ws + WS_IDX);

  prep<<<1952, 512, 0, stream>>>(xyz1, xyz2, lrf2, w_pos, pscale, pbias, w0,
                                 w1, feat2, posw, idxw, w0f, w0p, w1b, f2b);
  fgemm<<<32, 256, 0, stream>>>(f2b, w0f, F);
  h0_kernel<<<768, 256, 0, stream>>>(posw, idxw, w0p, F, s0, b0, H0);
  gemm2<<<512, 512, 0, stream>>>(H0, w1b, s1, b1, out);
}

// Round 11
// 232.168 us; speedup vs baseline: 1.1950x; 1.1950x over previous
//
#include <hip/hip_runtime.h>

// ---------------------------------------------------------------------------
// PointTransformerForSegmentation, round 16:
//   prep      : merged bf16 casts + kNN + pos embed (R9-proven)
//   fgemm     : F[b*128+n2][512] = feat2 . W0feat^T   (f32, tiny GEMM)
//   h0        : streaming H0 = relu((F[idx] + posw.W0p^T)*s0+b0), zero LDS.
//   gemm2     : 8-PHASE fine-interleaved schedule (T3+T4+T5) on the proven
//               geometry. BM=256 x BN=128, BK=64, 512 thr (8 waves 4Mx2N,
//               64x64/wave). Triple-buffered K-tiles (144 KB). Per tile,
//               4 phases: {stage-issue || vmcnt(8) (ph0 only) -> barrier ->
//               few ds_read -> lgkm(0) -> setprio 8xMFMA}; stages target the
//               FREE buffer ((kt+2)%3) so issues never wait on reads; vmcnt
//               never 0 in the main loop. 24 K-tiles (3 planes x 8);
//               register relu-fold at kt=7/15/23. R4 epilogue & algebra.
// LDS layout: fragment-linear 1KB groups (16 rows x 32 k), lane l at
// group*1024 + l*16 -> sequential banks, zero conflicts.
// ---------------------------------------------------------------------------

typedef unsigned short u16;
typedef __bf16 bf16x8 __attribute__((ext_vector_type(8)));
typedef float f32x4 __attribute__((ext_vector_type(4)));
typedef u16 u16x4 __attribute__((ext_vector_type(4)));
typedef u16 u16x8 __attribute__((ext_vector_type(8)));

#define BQ 8
#define N1Q 2048
#define N2Q 128
#define C2Q 256
#define DPOS 32
#define H0Q 512
#define H1Q 1024
#define NQ (BQ * N1Q)   // 16384 queries

// workspace layout (bytes)
#define WS_W0F 0u          // 512*256*2   = 262144
#define WS_W0P 262144u     // 512*32*2    = 32768
#define WS_W1 294912u      // 1024*512*2  = 1048576
#define WS_F2B 1343488u    // 1024*256*2  = 524288
#define WS_F 1867776u      // 1024*512*4  = 2097152
#define WS_H0 3964928u     // 3*16384*512*2 = 50331648
#define WS_POS 54296576u   // 3*16384*32*2 = 3145728
#define WS_IDX 57442304u   // 3*16384*4   = 196608 (end 57638912)

__device__ __forceinline__ u16 f2bf(float f) {
  unsigned int u = __builtin_bit_cast(unsigned int, f);
  return (u16)((u + 0x7FFFu + ((u >> 16) & 1u)) >> 16);
}

__device__ __forceinline__ void load16_lds(const void* g, void* l) {
  __builtin_amdgcn_global_load_lds(
      (const __attribute__((address_space(1))) unsigned int*)g,
      (__attribute__((address_space(3))) unsigned int*)l, 16, 0, 0);
}

// ---------------------------------------------------------------------------
// prep: blocks 0..127 = kNN + pos embed (128 queries/block); blocks 128..1951
// = bf16 conversions (512 elems/block).
__global__ __launch_bounds__(512, 2) void prep(
    const float* __restrict__ xyz1, const float* __restrict__ xyz2,
    const float* __restrict__ lrf2, const float* __restrict__ w_pos,
    const float* __restrict__ pscale, const float* __restrict__ pbias,
    const float* __restrict__ w0, const float* __restrict__ w1,
    const float* __restrict__ feat2,
    u16* __restrict__ posw, int* __restrict__ idxw,
    u16* __restrict__ w0f, u16* __restrict__ w0p,
    u16* __restrict__ w1b, u16* __restrict__ f2b) {
  if (blockIdx.x >= 128) {
    int i = (blockIdx.x - 128) * 512 + threadIdx.x;  // < 933888 exactly
    if (i < 131072) {
      int h = i >> 8, c = i & 255;
      w0f[i] = f2bf(w0[h * 288 + c]);
    } else if (i < 147456) {
      int j = i - 131072;
      int h = j >> 5, c = j & 31;
      w0p[j] = f2bf(w0[h * 288 + 256 + c]);
    } else if (i < 671744) {
      int j = i - 147456;
      w1b[j] = f2bf(w1[j]);
    } else {
      int j = i - 671744;  // < 262144
      f2b[j] = f2bf(feat2[j]);
    }
    return;
  }

  __shared__ float xyz2s[N2Q * 3];
  __shared__ float n2s[N2Q];
  __shared__ float lrfs[N2Q * 9];
  __shared__ float wps[DPOS * 4];
  __shared__ float pss[DPOS];
  __shared__ float pbs[DPOS];
  __shared__ float candd[128 * 13];  // stride 13: conflict-free merge reads
  __shared__ int candi[128 * 13];
  __shared__ int idxb[384];

  const int t = threadIdx.x;
  const int qb = blockIdx.x * 128;   // 128 knn blocks
  const int b = qb >> 11;

  for (int i = t; i < N2Q * 3; i += 512) xyz2s[i] = xyz2[b * N2Q * 3 + i];
  for (int i = t; i < N2Q * 9; i += 512) lrfs[i] = lrf2[b * N2Q * 9 + i];
  if (t < DPOS * 4) wps[t] = w_pos[t];
  if (t < DPOS) { pss[t] = pscale[t]; pbs[t] = pbias[t]; }
  __syncthreads();
  if (t < N2Q) {
    float x = xyz2s[t * 3], y = xyz2s[t * 3 + 1], z = xyz2s[t * 3 + 2];
    n2s[t] = x * x + y * y + z * z;
  }
  __syncthreads();

  // ---- 1a: partial kNN, 4 threads per query ----
  {
    const int ql = t >> 2, qt = t & 3;
    const int q = qb + ql;
    const float px = xyz1[q * 3], py = xyz1[q * 3 + 1], pz = xyz1[q * 3 + 2];
    const float pn = px * px + py * py + pz * pz;
    float d0 = 1e30f, d1 = 1e30f, d2v = 1e30f;
    int i0 = 0, i1 = 0, i2 = 0;
    const int ibeg = qt * 32;
    for (int i = ibeg; i < ibeg + 32; i++) {
      float dt = px * xyz2s[i * 3] + py * xyz2s[i * 3 + 1] + pz * xyz2s[i * 3 + 2];
      float d = pn + n2s[i] - 2.f * dt;
      if (d < d0) {
        d2v = d1; i2 = i1; d1 = d0; i1 = i0; d0 = d; i0 = i;
      } else if (d < d1) {
        d2v = d1; i2 = i1; d1 = d; i1 = i;
      } else if (d < d2v) {
        d2v = d; i2 = i;
      }
    }
    int base = ql * 13 + qt * 3;
    candd[base] = d0;      candi[base] = i0;
    candd[base + 1] = d1;  candi[base + 1] = i1;
    candd[base + 2] = d2v; candi[base + 2] = i2;
  }
  __syncthreads();

  // ---- 1b: merge 12 candidates per query (t<128), serial tie order ----
  if (t < 128) {
    float d0 = 1e30f, d1 = 1e30f, d2v = 1e30f;
    int i0 = 0, i1 = 0, i2 = 0;
    int base = t * 13;
#pragma unroll
    for (int c = 0; c < 12; c++) {
      float d = candd[base + c];
      int id = candi[base + c];
      if (d < d0) {
        d2v = d1; i2 = i1; d1 = d0; i1 = i0; d0 = d; i0 = id;
      } else if (d < d1) {
        d2v = d1; i2 = i1; d1 = d; i1 = id;
      } else if (d < d2v) {
        d2v = d; i2 = id;
      }
    }
    idxb[t] = i0;
    idxb[128 + t] = i1;
    idxb[256 + t] = i2;
  }
  __syncthreads();

  // ---- 1c: pos embed, one (query, neighbor) per thread (t<384) ----
  if (t < 384) {
    const int j = t >> 7, ql = t & 127;
    const int q = qb + ql;
    const float px = xyz1[q * 3], py = xyz1[q * 3 + 1], pz = xyz1[q * 3 + 2];
    const int id = idxb[j * 128 + ql];
    float rx = px - xyz2s[id * 3];
    float ry = py - xyz2s[id * 3 + 1];
    float rz = pz - xyz2s[id * 3 + 2];
    float rn = sqrtf(rx * rx + ry * ry + rz * rz);
    float inv = 1.f / fmaxf(rn, 1e-12f);
    float ux = rx * inv, uy = ry * inv, uz = rz * inv;
    const float* L = lrfs + id * 9;
    float a0 = L[0] * ux + L[1] * uy + L[2] * uz;
    float a1 = L[3] * ux + L[4] * uy + L[5] * uz;
    float a2 = L[6] * ux + L[7] * uy + L[8] * uz;
    const size_t row = (size_t)j * NQ + q;
    idxw[row] = id;
#pragma unroll
    for (int c = 0; c < 4; c++) {
      u16x8 chunk;
#pragma unroll
      for (int e = 0; e < 8; e++) {
        int o = c * 8 + e;
        float v = wps[o * 4] * rn + wps[o * 4 + 1] * a0 + wps[o * 4 + 2] * a1 +
                  wps[o * 4 + 3] * a2;
        v = v * pss[o] + pbs[o];
        v = (v >= 0.f) ? v : 0.2f * v;  // LeakyReLU(0.2)
        chunk[e] = f2bf(v);
      }
      *(u16x8*)(posw + row * 32 + c * 8) = chunk;
    }
  }
}

// ---------------------------------------------------------------------------
// fgemm: F[m][n] = sum_k feat2bf[m][k]*w0featbf[n][k], f32 out.
// M=1024 N=512 K=256, 128x128 tile, 32 blocks.
__global__ __launch_bounds__(256, 2) void fgemm(const u16* __restrict__ A,
                                                const u16* __restrict__ W,
                                                float* __restrict__ F) {
  __shared__ alignas(16) u16 As[128 * 32];
  __shared__ alignas(16) u16 Bs[128 * 32];
  const int m0 = (blockIdx.x >> 2) * 128, n0 = (blockIdx.x & 3) * 128;
  const int t = threadIdx.x;
  const int wv = t >> 6, lane = t & 63;
  const int wm = wv >> 1, wn = wv & 1;
  const int quad = lane >> 4, cc = lane & 15;
  const int srow = lane & 15, skc = quad * 8;
  f32x4 acc[4][4] = {};

  for (int k0 = 0; k0 < 256; k0 += 32) {
#pragma unroll
    for (int i = 0; i < 2; i++) {
      int g = i * 4 + wv;
      load16_lds(A + (size_t)(m0 + g * 16 + srow) * 256 + k0 + skc,
                 (char*)As + g * 1024 + (lane << 4));
      load16_lds(W + (size_t)(n0 + g * 16 + srow) * 256 + k0 + skc,
                 (char*)Bs + g * 1024 + (lane << 4));
    }
    __syncthreads();
    bf16x8 af[4], bf[4];
#pragma unroll
    for (int mt = 0; mt < 4; mt++)
      af[mt] = *(const bf16x8*)((const char*)As + (wm * 4 + mt) * 1024 + (lane << 4));
#pragma unroll
    for (int nt = 0; nt < 4; nt++)
      bf[nt] = *(const bf16x8*)((const char*)Bs + (wn * 4 + nt) * 1024 + (lane << 4));
#pragma unroll
    for (int mt = 0; mt < 4; mt++)
#pragma unroll
      for (int nt = 0; nt < 4; nt++)
        acc[mt][nt] = __builtin_amdgcn_mfma_f32_16x16x32_bf16(
            af[mt], bf[nt], acc[mt][nt], 0, 0, 0);
    __syncthreads();
  }

#pragma unroll
  for (int nt = 0; nt < 4; nt++) {
    int gn = n0 + wn * 64 + nt * 16 + cc;
#pragma unroll
    for (int mt = 0; mt < 4; mt++) {
      int gm = m0 + wm * 64 + mt * 16 + quad * 4;
#pragma unroll
      for (int r = 0; r < 4; r++)
        F[(size_t)(gm + r) * H0Q + gn] = acc[mt][nt][r];
    }
  }
}

// ---------------------------------------------------------------------------
// h0: streaming H0 build, zero LDS, 768 blocks x 256 threads (4 waves).
__global__ __launch_bounds__(256, 4) void h0_kernel(
    const u16* __restrict__ posw, const int* __restrict__ idxw,
    const u16* __restrict__ w0p, const float* __restrict__ F,
    const float* __restrict__ s0, const float* __restrict__ b0,
    u16* __restrict__ H0) {
  const int t = threadIdx.x;
  const int wv = t >> 6, lane = t & 63;
  const int quad = lane >> 4, cc = lane & 15;
  const int r0 = (blockIdx.x * 4 + wv) * 16;  // 768*4*16 = 49152 rows

  const int r = r0 + cc;               // this lane's row
  const int q = r & (NQ - 1);
  const int bb = q >> 11;
  const int idv = idxw[r];
  const float* Fr = F + ((size_t)(bb * N2Q + idv)) * H0Q;
  u16* Hr = H0 + (size_t)r * H0Q;

  const bf16x8 afr = *(const bf16x8*)(posw + (size_t)r * 32 + quad * 8);
  const f32x4 zf = {};

#pragma unroll 4
  for (int nt = 0; nt < 32; nt++) {
    const bf16x8 bfr = *(const bf16x8*)(w0p + (nt * 16 + cc) * 32 + quad * 8);
    f32x4 acc = __builtin_amdgcn_mfma_f32_16x16x32_bf16(bfr, afr, zf, 0, 0, 0);
    const int hb = nt * 16 + quad * 4;
    const f32x4 sv = *(const f32x4*)(s0 + hb);
    const f32x4 bv = *(const f32x4*)(b0 + hb);
    const f32x4 fv = *(const f32x4*)(Fr + hb);
    u16x4 o4;
#pragma unroll
    for (int e = 0; e < 4; e++) {
      float h = (fv[e] + acc[e]) * sv[e] + bv[e];
      h = h > 0.f ? h : 0.f;
      o4[e] = f2bf(h);
    }
    *(u16x4*)(Hr + hb) = o4;
  }
}

// ---------------------------------------------------------------------------
// gemm2: out[b][n][n1] = sum_j relu((H0_j[q][:] . W1[n][:])*s1[n] + b1[n]).
// 8-PHASE schedule. BM=256 x BN=128, BK=64, 512 thr = 8 waves (4M x 2N),
// 64x64 per wave. Triple-buffered (A 32KB + B 16KB per tile = 144 KB).
// Per K-tile kt (buffer bi=kt%3; stages go to FREE buffer (kt+2)%3):
//  ph0: stage A(2) -> vmcnt(8) -> BAR -> ds_read af0[4],bf0[2] -> lgkm0 ->
//       prio1 8xMFMA(kk0,nt01) prio0
//  ph1: stage A(2) -> BAR -> ds_read bf0[2] -> lgkm0 -> 8xMFMA(kk0,nt23)
//  ph2: stage B(2) -> BAR -> ds_read af1[4],bf1[2] -> lgkm0 -> 8xMFMA(kk1,nt01)
//  ph3: BAR -> ds_read bf1[2] -> lgkm0 -> 8xMFMA(kk1,nt23) -> fold@7/15/23
// vmcnt never 0 in main loop (counts: next tile 6 + 2 just-issued = 8).
// Tail kt=22 (vmcnt 6), kt=23 (vmcnt 0), no stages.
__global__ __launch_bounds__(512, 2) void gemm2(const u16* __restrict__ A,
                                                const u16* __restrict__ W,
                                                const float* __restrict__ s,
                                                const float* __restrict__ bz,
                                                float* __restrict__ out) {
  __shared__ alignas(16) u16 As[3][256 * 64];  // 32 KB per buffer
  __shared__ alignas(16) u16 Bs[3][128 * 64];  // 16 KB per buffer
  const int id = blockIdx.x;            // 512 blocks
  const int xcd = id & 7, g = id >> 3;  // g 0..63
  const int m0 = (xcd * 8 + (g >> 3)) * 256;  // 8 m-tiles (256-row) per XCD
  const int n0 = (g & 7) * 128;
  const int t = threadIdx.x;
  const int wv = t >> 6, lane = t & 63;
  const int wm = wv >> 1, wn = wv & 1;  // 4M x 2N wave grid
  const int quad = lane >> 4, cc = lane & 15;
  const int lr = lane & 15, lk = quad * 8;

  float sv[4], bv[4];
#pragma unroll
  for (int nt = 0; nt < 4; nt++) {
    int gn = n0 + wn * 64 + nt * 16 + cc;
    sv[nt] = s[gn];
    bv[nt] = bz[gn];
  }

  // stage 2 A-loads (half = 0: rowgroups wv, 8+wv at kk0; half = 1: same at kk1)
  auto stageA2 = [&](int st, int half) {
    const int bi2 = st % 3;
    const u16* Ap = A + (size_t)(st >> 3) * ((size_t)NQ * H0Q) + ((st & 7) << 6);
    char* ab = (char*)As[bi2] + (lane << 4);
    const int kk = half;
#pragma unroll
    for (int ii = 0; ii < 2; ii++) {
      const int rg = ii * 8 + wv;
      load16_lds(Ap + (size_t)(m0 + rg * 16 + lr) * 512 + kk * 32 + lk,
                 ab + (kk * 16 + rg) * 1024);
    }
  };
  // stage 2 B-loads (colgroup wv at kk0 and kk1)
  auto stageB2 = [&](int st) {
    const int bi2 = st % 3;
    const u16* Wp = W + ((st & 7) << 6);
    char* bb = (char*)Bs[bi2] + (lane << 4);
#pragma unroll
    for (int kk = 0; kk < 2; kk++)
      load16_lds(Wp + (size_t)(n0 + wv * 16 + lr) * 512 + kk * 32 + lk,
                 bb + (kk * 8 + wv) * 1024);
  };

  f32x4 sum[4][4] = {};
  f32x4 acc[4][4] = {};

  auto fold = [&]() {
#pragma unroll
    for (int mt = 0; mt < 4; mt++)
#pragma unroll
      for (int nt = 0; nt < 4; nt++) {
#pragma unroll
        for (int r = 0; r < 4; r++) {
          float h = acc[mt][nt][r] * sv[nt] + bv[nt];
          sum[mt][nt][r] += (h > 0.f ? h : 0.f);
        }
        acc[mt][nt] = f32x4{};
      }
  };

  // one K-tile = 4 phases; stages for tile kt+2 (if doStage)
  auto tile4 = [&](int bi2, int st, bool doStage) {
    const char* ab = (const char*)As[bi2] + (lane << 4);
    const char* bb = (const char*)Bs[bi2] + (lane << 4);
    bf16x8 af[4], bf[4];
    // ---- ph0 (vmcnt done by caller before BAR) ----
    __builtin_amdgcn_s_barrier();
#pragma unroll
    for (int mt = 0; mt < 4; mt++)
      af[mt] = *(const bf16x8*)(ab + (wm * 4 + mt) * 1024);
#pragma unroll
    for (int nt = 0; nt < 2; nt++)
      bf[nt] = *(const bf16x8*)(bb + (wn * 4 + nt) * 1024);
    asm volatile("s_waitcnt lgkmcnt(0)" ::: "memory");
    __builtin_amdgcn_s_setprio(1);
#pragma unroll
    for (int mt = 0; mt < 4; mt++)
#pragma unroll
      for (int nt = 0; nt < 2; nt++)
        acc[mt][nt] = __builtin_amdgcn_mfma_f32_16x16x32_bf16(
            af[mt], bf[nt], acc[mt][nt], 0, 0, 0);
    __builtin_amdgcn_s_setprio(0);
    // ---- ph1 ----
    if (doStage) stageA2(st, 1);
    __builtin_amdgcn_s_barrier();
#pragma unroll
    for (int nt = 2; nt < 4; nt++)
      bf[nt] = *(const bf16x8*)(bb + (wn * 4 + nt) * 1024);
    asm volatile("s_waitcnt lgkmcnt(0)" ::: "memory");
    __builtin_amdgcn_s_setprio(1);
#pragma unroll
    for (int mt = 0; mt < 4; mt++)
#pragma unroll
      for (int nt = 2; nt < 4; nt++)
        acc[mt][nt] = __builtin_amdgcn_mfma_f32_16x16x32_bf16(
            af[mt], bf[nt], acc[mt][nt], 0, 0, 0);
    __builtin_amdgcn_s_setprio(0);
    // ---- ph2 (kk=1) ----
    if (doStage) stageB2(st);
    __builtin_amdgcn_s_barrier();
#pragma unroll
    for (int mt = 0; mt < 4; mt++)
      af[mt] = *(const bf16x8*)(ab + (16 + wm * 4 + mt) * 1024);
#pragma unroll
    for (int nt = 0; nt < 2; nt++)
      bf[nt] = *(const bf16x8*)(bb + (8 + wn * 4 + nt) * 1024);
    asm volatile("s_waitcnt lgkmcnt(0)" ::: "memory");
    __builtin_amdgcn_s_setprio(1);
#pragma unroll
    for (int mt = 0; mt < 4; mt++)
#pragma unroll
      for (int nt = 0; nt < 2; nt++)
        acc[mt][nt] = __builtin_amdgcn_mfma_f32_16x16x32_bf16(
            af[mt], bf[nt], acc[mt][nt], 0, 0, 0);
    __builtin_amdgcn_s_setprio(0);
    // ---- ph3 ----
    __builtin_amdgcn_s_barrier();
#pragma unroll
    for (int nt = 2; nt < 4; nt++)
      bf[nt] = *(const bf16x8*)(bb + (8 + wn * 4 + nt) * 1024);
    asm volatile("s_waitcnt lgkmcnt(0)" ::: "memory");
    __builtin_amdgcn_s_setprio(1);
#pragma unroll
    for (int mt = 0; mt < 4; mt++)
#pragma unroll
      for (int nt = 2; nt < 4; nt++)
        acc[mt][nt] = __builtin_amdgcn_mfma_f32_16x16x32_bf16(
            af[mt], bf[nt], acc[mt][nt], 0, 0, 0);
    __builtin_amdgcn_s_setprio(0);
  };

  // prologue: fully stage tiles 0 and 1
  stageA2(0, 0); stageA2(0, 1); stageB2(0);
  stageA2(1, 0); stageA2(1, 1); stageB2(1);

#pragma unroll 3
  for (int kt = 0; kt < 22; kt++) {
    const int bi = kt % 3;
    stageA2(kt + 2, 0);                               // ph0 stage (free buf)
    asm volatile("s_waitcnt vmcnt(8)" ::: "memory");  // tile kt landed
    tile4(bi, kt + 2, true);
    if ((kt & 7) == 7) fold();                        // kt 7, 15
  }
  {  // kt = 22: no stages, tile 23's 6 loads outstanding
    asm volatile("s_waitcnt vmcnt(6)" ::: "memory");
    tile4(22 % 3, 0, false);
  }
  {  // kt = 23
    asm volatile("s_waitcnt vmcnt(0)" ::: "memory");
    tile4(23 % 3, 0, false);
    fold();
  }

  // epilogue (R4-identical mapping)
#pragma unroll
  for (int nt = 0; nt < 4; nt++) {
    int gn = n0 + wn * 64 + nt * 16 + cc;
#pragma unroll
    for (int mt = 0; mt < 4; mt++) {
      int gm = m0 + wm * 64 + mt * 16 + quad * 4;
#pragma unroll
      for (int r = 0; r < 4; r++) {
        int q = gm + r;
        out[((size_t)(q >> 11) * H1Q + gn) * N1Q + (q & 2047)] = sum[mt][nt][r];
      }
    }
  }
}

// ---------------------------------------------------------------------------
extern "C" void kernel_launch(void* const* d_in, const int* in_sizes, int n_in,
                              void* d_out, int out_size, void* d_ws,
                              size_t ws_size, hipStream_t stream) {
  const float* xyz1 = (const float*)d_in[0];
  const float* xyz2 = (const float*)d_in[1];
  const float* feat2 = (const float*)d_in[2];
  const float* lrf2 = (const float*)d_in[3];
  const float* w_pos = (const float*)d_in[4];
  const float* pscale = (const float*)d_in[5];
  const float* pbias = (const float*)d_in[6];
  const float* w0 = (const float*)d_in[7];
  const float* s0 = (const float*)d_in[8];
  const float* b0 = (const float*)d_in[9];
  const float* w1 = (const float*)d_in[10];
  const float* s1 = (const float*)d_in[11];
  const float* b1 = (const float*)d_in[12];
  float* out = (float*)d_out;

  char* ws = (char*)d_ws;
  u16* w0f = (u16*)(ws + WS_W0F);
  u16* w0p = (u16*)(ws + WS_W0P);
  u16* w1b = (u16*)(ws + WS_W1);
  u16* f2b = (u16*)(ws + WS_F2B);
  float* F = (float*)(ws + WS_F);
  u16* H0 = (u16*)(ws + WS_H0);
  u16* posw = (u16*)(ws + WS_POS);
  int* idxw = (int*)(ws + WS_IDX);

  prep<<<1952, 512, 0, stream>>>(xyz1, xyz2, lrf2, w_pos, pscale, pbias, w0,
                                 w1, feat2, posw, idxw, w0f, w0p, w1b, f2b);
  fgemm<<<32, 256, 0, stream>>>(f2b, w0f, F);
  h0_kernel<<<768, 256, 0, stream>>>(posw, idxw, w0p, F, s0, b0, H0);
  gemm2<<<512, 512, 0, stream>>>(H0, w1b, s1, b1, out);
}

// Round 12
// 201.641 us; speedup vs baseline: 1.3759x; 1.1514x over previous
//
#include <hip/hip_runtime.h>

// ---------------------------------------------------------------------------
// PointTransformerForSegmentation, round 17:
//   prep      : merged bf16 casts + kNN + pos embed (R9-proven)
//   fgemm     : F[b*128+n2][512] = feat2 . W0feat^T   (f32, tiny GEMM)
//   h0        : streaming H0 = relu((F[idx] + posw.W0p^T)*s0+b0), zero LDS.
//   gemm2     : PLANE-INTERLEAVED byte-cut GEMM. Evidence from R1-R11:
//               dur ~= staged_bytes / ~6.5-7.5 TB/s regardless of schedule
//               (603MB->94us, 804MB->108, 904->121, 1.6GB->188). So: stage B
//               ONCE per K-chunk (planes inner, 3 live accumulators) ->
//               bytes 603 -> 335 MB. BM=128 x BN=256, BK=32, 16 K-steps,
//               48 MFMA/wave/step, ONE barrier/step (all ds_reads consumed
//               by in-step MFMAs -> no read-vs-DMA hazard), triple-buffered
//               40KB units (120KB LDS), counted vmcnt(5). No sum registers:
//               out = sum_j relu(acc_j*s+b) at epilogue. acc=192 VGPR,
//               launch_bounds(512,2) caps at 256.
// LDS layout: fragment-linear 1KB groups (16 rows x 32 k), lane l at
// group*1024 + l*16 -> sequential banks, zero conflicts.
// ---------------------------------------------------------------------------

typedef unsigned short u16;
typedef __bf16 bf16x8 __attribute__((ext_vector_type(8)));
typedef float f32x4 __attribute__((ext_vector_type(4)));
typedef u16 u16x4 __attribute__((ext_vector_type(4)));
typedef u16 u16x8 __attribute__((ext_vector_type(8)));

#define BQ 8
#define N1Q 2048
#define N2Q 128
#define C2Q 256
#define DPOS 32
#define H0Q 512
#define H1Q 1024
#define NQ (BQ * N1Q)   // 16384 queries

// workspace layout (bytes)
#define WS_W0F 0u          // 512*256*2   = 262144
#define WS_W0P 262144u     // 512*32*2    = 32768
#define WS_W1 294912u      // 1024*512*2  = 1048576
#define WS_F2B 1343488u    // 1024*256*2  = 524288
#define WS_F 1867776u      // 1024*512*4  = 2097152
#define WS_H0 3964928u     // 3*16384*512*2 = 50331648
#define WS_POS 54296576u   // 3*16384*32*2 = 3145728
#define WS_IDX 57442304u   // 3*16384*4   = 196608 (end 57638912)

__device__ __forceinline__ u16 f2bf(float f) {
  unsigned int u = __builtin_bit_cast(unsigned int, f);
  return (u16)((u + 0x7FFFu + ((u >> 16) & 1u)) >> 16);
}

__device__ __forceinline__ void load16_lds(const void* g, void* l) {
  __builtin_amdgcn_global_load_lds(
      (const __attribute__((address_space(1))) unsigned int*)g,
      (__attribute__((address_space(3))) unsigned int*)l, 16, 0, 0);
}

// ---------------------------------------------------------------------------
// prep: blocks 0..127 = kNN + pos embed (128 queries/block); blocks 128..1951
// = bf16 conversions (512 elems/block).
__global__ __launch_bounds__(512, 2) void prep(
    const float* __restrict__ xyz1, const float* __restrict__ xyz2,
    const float* __restrict__ lrf2, const float* __restrict__ w_pos,
    const float* __restrict__ pscale, const float* __restrict__ pbias,
    const float* __restrict__ w0, const float* __restrict__ w1,
    const float* __restrict__ feat2,
    u16* __restrict__ posw, int* __restrict__ idxw,
    u16* __restrict__ w0f, u16* __restrict__ w0p,
    u16* __restrict__ w1b, u16* __restrict__ f2b) {
  if (blockIdx.x >= 128) {
    int i = (blockIdx.x - 128) * 512 + threadIdx.x;  // < 933888 exactly
    if (i < 131072) {
      int h = i >> 8, c = i & 255;
      w0f[i] = f2bf(w0[h * 288 + c]);
    } else if (i < 147456) {
      int j = i - 131072;
      int h = j >> 5, c = j & 31;
      w0p[j] = f2bf(w0[h * 288 + 256 + c]);
    } else if (i < 671744) {
      int j = i - 147456;
      w1b[j] = f2bf(w1[j]);
    } else {
      int j = i - 671744;  // < 262144
      f2b[j] = f2bf(feat2[j]);
    }
    return;
  }

  __shared__ float xyz2s[N2Q * 3];
  __shared__ float n2s[N2Q];
  __shared__ float lrfs[N2Q * 9];
  __shared__ float wps[DPOS * 4];
  __shared__ float pss[DPOS];
  __shared__ float pbs[DPOS];
  __shared__ float candd[128 * 13];  // stride 13: conflict-free merge reads
  __shared__ int candi[128 * 13];
  __shared__ int idxb[384];

  const int t = threadIdx.x;
  const int qb = blockIdx.x * 128;   // 128 knn blocks
  const int b = qb >> 11;

  for (int i = t; i < N2Q * 3; i += 512) xyz2s[i] = xyz2[b * N2Q * 3 + i];
  for (int i = t; i < N2Q * 9; i += 512) lrfs[i] = lrf2[b * N2Q * 9 + i];
  if (t < DPOS * 4) wps[t] = w_pos[t];
  if (t < DPOS) { pss[t] = pscale[t]; pbs[t] = pbias[t]; }
  __syncthreads();
  if (t < N2Q) {
    float x = xyz2s[t * 3], y = xyz2s[t * 3 + 1], z = xyz2s[t * 3 + 2];
    n2s[t] = x * x + y * y + z * z;
  }
  __syncthreads();

  // ---- 1a: partial kNN, 4 threads per query ----
  {
    const int ql = t >> 2, qt = t & 3;
    const int q = qb + ql;
    const float px = xyz1[q * 3], py = xyz1[q * 3 + 1], pz = xyz1[q * 3 + 2];
    const float pn = px * px + py * py + pz * pz;
    float d0 = 1e30f, d1 = 1e30f, d2v = 1e30f;
    int i0 = 0, i1 = 0, i2 = 0;
    const int ibeg = qt * 32;
    for (int i = ibeg; i < ibeg + 32; i++) {
      float dt = px * xyz2s[i * 3] + py * xyz2s[i * 3 + 1] + pz * xyz2s[i * 3 + 2];
      float d = pn + n2s[i] - 2.f * dt;
      if (d < d0) {
        d2v = d1; i2 = i1; d1 = d0; i1 = i0; d0 = d; i0 = i;
      } else if (d < d1) {
        d2v = d1; i2 = i1; d1 = d; i1 = i;
      } else if (d < d2v) {
        d2v = d; i2 = i;
      }
    }
    int base = ql * 13 + qt * 3;
    candd[base] = d0;      candi[base] = i0;
    candd[base + 1] = d1;  candi[base + 1] = i1;
    candd[base + 2] = d2v; candi[base + 2] = i2;
  }
  __syncthreads();

  // ---- 1b: merge 12 candidates per query (t<128), serial tie order ----
  if (t < 128) {
    float d0 = 1e30f, d1 = 1e30f, d2v = 1e30f;
    int i0 = 0, i1 = 0, i2 = 0;
    int base = t * 13;
#pragma unroll
    for (int c = 0; c < 12; c++) {
      float d = candd[base + c];
      int id = candi[base + c];
      if (d < d0) {
        d2v = d1; i2 = i1; d1 = d0; i1 = i0; d0 = d; i0 = id;
      } else if (d < d1) {
        d2v = d1; i2 = i1; d1 = d; i1 = id;
      } else if (d < d2v) {
        d2v = d; i2 = id;
      }
    }
    idxb[t] = i0;
    idxb[128 + t] = i1;
    idxb[256 + t] = i2;
  }
  __syncthreads();

  // ---- 1c: pos embed, one (query, neighbor) per thread (t<384) ----
  if (t < 384) {
    const int j = t >> 7, ql = t & 127;
    const int q = qb + ql;
    const float px = xyz1[q * 3], py = xyz1[q * 3 + 1], pz = xyz1[q * 3 + 2];
    const int id = idxb[j * 128 + ql];
    float rx = px - xyz2s[id * 3];
    float ry = py - xyz2s[id * 3 + 1];
    float rz = pz - xyz2s[id * 3 + 2];
    float rn = sqrtf(rx * rx + ry * ry + rz * rz);
    float inv = 1.f / fmaxf(rn, 1e-12f);
    float ux = rx * inv, uy = ry * inv, uz = rz * inv;
    const float* L = lrfs + id * 9;
    float a0 = L[0] * ux + L[1] * uy + L[2] * uz;
    float a1 = L[3] * ux + L[4] * uy + L[5] * uz;
    float a2 = L[6] * ux + L[7] * uy + L[8] * uz;
    const size_t row = (size_t)j * NQ + q;
    idxw[row] = id;
#pragma unroll
    for (int c = 0; c < 4; c++) {
      u16x8 chunk;
#pragma unroll
      for (int e = 0; e < 8; e++) {
        int o = c * 8 + e;
        float v = wps[o * 4] * rn + wps[o * 4 + 1] * a0 + wps[o * 4 + 2] * a1 +
                  wps[o * 4 + 3] * a2;
        v = v * pss[o] + pbs[o];
        v = (v >= 0.f) ? v : 0.2f * v;  // LeakyReLU(0.2)
        chunk[e] = f2bf(v);
      }
      *(u16x8*)(posw + row * 32 + c * 8) = chunk;
    }
  }
}

// ---------------------------------------------------------------------------
// fgemm: F[m][n] = sum_k feat2bf[m][k]*w0featbf[n][k], f32 out.
// M=1024 N=512 K=256, 128x128 tile, 32 blocks.
__global__ __launch_bounds__(256, 2) void fgemm(const u16* __restrict__ A,
                                                const u16* __restrict__ W,
                                                float* __restrict__ F) {
  __shared__ alignas(16) u16 As[128 * 32];
  __shared__ alignas(16) u16 Bs[128 * 32];
  const int m0 = (blockIdx.x >> 2) * 128, n0 = (blockIdx.x & 3) * 128;
  const int t = threadIdx.x;
  const int wv = t >> 6, lane = t & 63;
  const int wm = wv >> 1, wn = wv & 1;
  const int quad = lane >> 4, cc = lane & 15;
  const int srow = lane & 15, skc = quad * 8;
  f32x4 acc[4][4] = {};

  for (int k0 = 0; k0 < 256; k0 += 32) {
#pragma unroll
    for (int i = 0; i < 2; i++) {
      int g = i * 4 + wv;
      load16_lds(A + (size_t)(m0 + g * 16 + srow) * 256 + k0 + skc,
                 (char*)As + g * 1024 + (lane << 4));
      load16_lds(W + (size_t)(n0 + g * 16 + srow) * 256 + k0 + skc,
                 (char*)Bs + g * 1024 + (lane << 4));
    }
    __syncthreads();
    bf16x8 af[4], bf[4];
#pragma unroll
    for (int mt = 0; mt < 4; mt++)
      af[mt] = *(const bf16x8*)((const char*)As + (wm * 4 + mt) * 1024 + (lane << 4));
#pragma unroll
    for (int nt = 0; nt < 4; nt++)
      bf[nt] = *(const bf16x8*)((const char*)Bs + (wn * 4 + nt) * 1024 + (lane << 4));
#pragma unroll
    for (int mt = 0; mt < 4; mt++)
#pragma unroll
      for (int nt = 0; nt < 4; nt++)
        acc[mt][nt] = __builtin_amdgcn_mfma_f32_16x16x32_bf16(
            af[mt], bf[nt], acc[mt][nt], 0, 0, 0);
    __syncthreads();
  }

#pragma unroll
  for (int nt = 0; nt < 4; nt++) {
    int gn = n0 + wn * 64 + nt * 16 + cc;
#pragma unroll
    for (int mt = 0; mt < 4; mt++) {
      int gm = m0 + wm * 64 + mt * 16 + quad * 4;
#pragma unroll
      for (int r = 0; r < 4; r++)
        F[(size_t)(gm + r) * H0Q + gn] = acc[mt][nt][r];
    }
  }
}

// ---------------------------------------------------------------------------
// h0: streaming H0 build, zero LDS, 768 blocks x 256 threads (4 waves).
__global__ __launch_bounds__(256, 4) void h0_kernel(
    const u16* __restrict__ posw, const int* __restrict__ idxw,
    const u16* __restrict__ w0p, const float* __restrict__ F,
    const float* __restrict__ s0, const float* __restrict__ b0,
    u16* __restrict__ H0) {
  const int t = threadIdx.x;
  const int wv = t >> 6, lane = t & 63;
  const int quad = lane >> 4, cc = lane & 15;
  const int r0 = (blockIdx.x * 4 + wv) * 16;  // 768*4*16 = 49152 rows

  const int r = r0 + cc;               // this lane's row
  const int q = r & (NQ - 1);
  const int bb = q >> 11;
  const int idv = idxw[r];
  const float* Fr = F + ((size_t)(bb * N2Q + idv)) * H0Q;
  u16* Hr = H0 + (size_t)r * H0Q;

  const bf16x8 afr = *(const bf16x8*)(posw + (size_t)r * 32 + quad * 8);
  const f32x4 zf = {};

#pragma unroll 4
  for (int nt = 0; nt < 32; nt++) {
    const bf16x8 bfr = *(const bf16x8*)(w0p + (nt * 16 + cc) * 32 + quad * 8);
    f32x4 acc = __builtin_amdgcn_mfma_f32_16x16x32_bf16(bfr, afr, zf, 0, 0, 0);
    const int hb = nt * 16 + quad * 4;
    const f32x4 sv = *(const f32x4*)(s0 + hb);
    const f32x4 bv = *(const f32x4*)(b0 + hb);
    const f32x4 fv = *(const f32x4*)(Fr + hb);
    u16x4 o4;
#pragma unroll
    for (int e = 0; e < 4; e++) {
      float h = (fv[e] + acc[e]) * sv[e] + bv[e];
      h = h > 0.f ? h : 0.f;
      o4[e] = f2bf(h);
    }
    *(u16x4*)(Hr + hb) = o4;
  }
}

// ---------------------------------------------------------------------------
// gemm2: out[b][n][n1] = sum_j relu((H0_j[q][:] . W1[n][:])*s1[n] + b1[n]).
// PLANE-INTERLEAVED: BM=128 x BN=256, BK=32, 16 K-steps; per step stage
// {A-plane0,1,2 (24KB) + B (16KB)} with B staged ONCE (planes share it),
// then 48 MFMA/wave (16 per plane into acc[j]). Staged bytes: 335 MB
// (vs 603 for plane-sequential) -- the R1-R11 delivery-rate model says
// this is the lever. ONE barrier per step (every ds_read is consumed by
// an in-step MFMA before the barrier; staged buffer is 2 steps ahead).
// Triple-buffered 40KB units (120KB). Counted vmcnt(5). No sum regs:
// epilogue out = sum_j relu(acc_j*s1+b1).
__global__ __launch_bounds__(512, 2) void gemm2(const u16* __restrict__ A,
                                                const u16* __restrict__ W,
                                                const float* __restrict__ s,
                                                const float* __restrict__ bz,
                                                float* __restrict__ out) {
  __shared__ alignas(16) char smem[3][40960];  // A 3x8KB + B 16KB per buffer
  const int id = blockIdx.x;            // 512 blocks
  const int xcd = id & 7, g = id >> 3;  // g 0..63
  const int m0 = (xcd * 16 + (g >> 2)) * 128;  // 16 m-tiles per XCD
  const int n0 = (g & 3) * 256;
  const int t = threadIdx.x;
  const int wv = t >> 6, lane = t & 63;
  const int wm = wv >> 2, wn = wv & 3;  // 2M x 4N wave grid, 64x64 per wave
  const int quad = lane >> 4, cc = lane & 15;
  const int lr = lane & 15, lk = quad * 8;

  // staging source bases (elements); +kt*32 per step; A: +plane*NQ*H0Q
  const size_t aOff = (size_t)(m0 + wv * 16 + lr) * 512 + lk;
  size_t bOff[2];
#pragma unroll
  for (int i = 0; i < 2; i++)
    bOff[i] = (size_t)(n0 + (wv * 2 + i) * 16 + lr) * 512 + lk;

  auto stage = [&](int kt, int buf) {
    const int k0 = kt << 5;
    char* dst = smem[buf] + (lane << 4);
#pragma unroll
    for (int j = 0; j < 3; j++)
      load16_lds(A + (size_t)j * NQ * H0Q + aOff + k0,
                 dst + j * 8192 + wv * 1024);
#pragma unroll
    for (int i = 0; i < 2; i++)
      load16_lds(W + bOff[i] + k0, dst + 24576 + (wv * 2 + i) * 1024);
  };

  f32x4 acc[3][4][4] = {};  // 192 VGPR: 3 planes x 64x64 wave tile

  stage(0, 0);
  stage(1, 1);

  int bi = 0, sb = 2;
  for (int kt = 0; kt < 16; kt++) {
    if (kt < 15)
      asm volatile("s_waitcnt vmcnt(5)" ::: "memory");  // tile kt landed
    else
      asm volatile("s_waitcnt vmcnt(0)" ::: "memory");
    __builtin_amdgcn_s_barrier();  // all waves past step kt-1 (reads done)
    if (kt + 2 < 16) {
      stage(kt + 2, sb);           // overwrite buf of tile kt-1: safe
      sb = (sb == 2) ? 0 : sb + 1;
    }
    const char* base = smem[bi] + (lane << 4);
    bf16x8 bf[4];
#pragma unroll
    for (int nt = 0; nt < 4; nt++)
      bf[nt] = *(const bf16x8*)(base + 24576 + (wn * 4 + nt) * 1024);
#pragma unroll
    for (int j = 0; j < 3; j++) {
      bf16x8 af[4];
#pragma unroll
      for (int mt = 0; mt < 4; mt++)
        af[mt] = *(const bf16x8*)(base + j * 8192 + (wm * 4 + mt) * 1024);
      __builtin_amdgcn_s_setprio(1);
#pragma unroll
      for (int mt = 0; mt < 4; mt++)
#pragma unroll
        for (int nt = 0; nt < 4; nt++)
          acc[j][mt][nt] = __builtin_amdgcn_mfma_f32_16x16x32_bf16(
              af[mt], bf[nt], acc[j][mt][nt], 0, 0, 0);
      __builtin_amdgcn_s_setprio(0);
    }
    bi = (bi == 2) ? 0 : bi + 1;
  }

  // epilogue: out = sum_j relu(acc_j * s1 + b1)
#pragma unroll
  for (int nt = 0; nt < 4; nt++) {
    int gn = n0 + wn * 64 + nt * 16 + cc;
    float sv = s[gn], bv = bz[gn];
#pragma unroll
    for (int mt = 0; mt < 4; mt++) {
      int gm = m0 + wm * 64 + mt * 16 + quad * 4;
#pragma unroll
      for (int r = 0; r < 4; r++) {
        float h0v = acc[0][mt][nt][r] * sv + bv;
        float h1v = acc[1][mt][nt][r] * sv + bv;
        float h2v = acc[2][mt][nt][r] * sv + bv;
        float v = (h0v > 0.f ? h0v : 0.f) + (h1v > 0.f ? h1v : 0.f) +
                  (h2v > 0.f ? h2v : 0.f);
        int q = gm + r;
        out[((size_t)(q >> 11) * H1Q + gn) * N1Q + (q & 2047)] = v;
      }
    }
  }
}

// ---------------------------------------------------------------------------
extern "C" void kernel_launch(void* const* d_in, const int* in_sizes, int n_in,
                              void* d_out, int out_size, void* d_ws,
                              size_t ws_size, hipStream_t stream) {
  const float* xyz1 = (const float*)d_in[0];
  const float* xyz2 = (const float*)d_in[1];
  const float* feat2 = (const float*)d_in[2];
  const float* lrf2 = (const float*)d_in[3];
  const float* w_pos = (const float*)d_in[4];
  const float* pscale = (const float*)d_in[5];
  const float* pbias = (const float*)d_in[6];
  const float* w0 = (const float*)d_in[7];
  const float* s0 = (const float*)d_in[8];
  const float* b0 = (const float*)d_in[9];
  const float* w1 = (const float*)d_in[10];
  const float* s1 = (const float*)d_in[11];
  const float* b1 = (const float*)d_in[12];
  float* out = (float*)d_out;

  char* ws = (char*)d_ws;
  u16* w0f = (u16*)(ws + WS_W0F);
  u16* w0p = (u16*)(ws + WS_W0P);
  u16* w1b = (u16*)(ws + WS_W1);
  u16* f2b = (u16*)(ws + WS_F2B);
  float* F = (float*)(ws + WS_F);
  u16* H0 = (u16*)(ws + WS_H0);
  u16* posw = (u16*)(ws + WS_POS);
  int* idxw = (int*)(ws + WS_IDX);

  prep<<<1952, 512, 0, stream>>>(xyz1, xyz2, lrf2, w_pos, pscale, pbias, w0,
                                 w1, feat2, posw, idxw, w0f, w0p, w1b, f2b);
  fgemm<<<32, 256, 0, stream>>>(f2b, w0f, F);
  h0_kernel<<<768, 256, 0, stream>>>(posw, idxw, w0p, F, s0, b0, H0);
  gemm2<<<512, 512, 0, stream>>>(H0, w1b, s1, b1, out);
}